// Round 4
// baseline (557.580 us; speedup 1.0000x reference)
//
#include <hip/hip_runtime.h>

#define EPS_LN 1e-5f
#define EPS_BN 1e-5f

__device__ __forceinline__ float lrelu(float v) { return v >= 0.f ? v : 0.2f * v; }

// ---------------------------------------------------------------------------
// Kernel A: GAT1 (+ReLU) -> GAT2 -> LayerNorm + residual -> Linear + ReLU
// Single block; N=48, E=768+48 self loops = 816. Everything lives in LDS.
// ---------------------------------------------------------------------------
__global__ __launch_bounds__(512) void kA(
    const float* __restrict__ obj, const int* __restrict__ eidx,
    const float* __restrict__ W1, const float* __restrict__ as1w,
    const float* __restrict__ ad1w, const float* __restrict__ b1,
    const float* __restrict__ W2, const float* __restrict__ as2w,
    const float* __restrict__ ad2w, const float* __restrict__ b2,
    const float* __restrict__ lng, const float* __restrict__ lnb,
    const float* __restrict__ linW, const float* __restrict__ linb,
    float* __restrict__ hlin)
{
  const int tid = threadIdx.x;
  __shared__ float xin[48][9];
  __shared__ float h1[48][32];
  __shared__ float a1s[48][4], a1d[48][4];
  __shared__ float m1[48][4], d1[48][4];
  __shared__ float x2[48][32];
  __shared__ float h2s[48][9];
  __shared__ float a2s[48], a2d[48], m2[48], d2[48];
  __shared__ float g2[48][9];
  __shared__ float xl[48][9];
  __shared__ int srcl[816], tgtl[816], elist[816];
  __shared__ int offs[49], cnt[48];

  for (int i = tid; i < 768; i += 512) { srcl[i] = eidx[i]; tgtl[i] = eidx[768 + i]; }
  if (tid < 48) { srcl[768 + tid] = tid; tgtl[768 + tid] = tid; }   // self loops
  for (int i = tid; i < 432; i += 512) xin[i / 9][i % 9] = obj[i];
  __syncthreads();

  // CSR over target nodes (deterministic edge order)
  if (tid < 48) { int c = 0; for (int e = 0; e < 816; ++e) c += (tgtl[e] == tid); cnt[tid] = c; }
  __syncthreads();
  if (tid == 0) { offs[0] = 0; for (int n = 0; n < 48; ++n) offs[n + 1] = offs[n] + cnt[n]; }
  __syncthreads();
  if (tid < 48) { int p = offs[tid]; for (int e = 0; e < 816; ++e) if (tgtl[e] == tid) elist[p++] = e; }

  // h1 = x @ W1  (48x32), independent of elist fill above
  for (int i = tid; i < 1536; i += 512) {
    int n = i >> 5, j = i & 31;
    float s = 0.f;
    for (int f = 0; f < 9; ++f) s += xin[n][f] * W1[f * 32 + j];
    h1[n][j] = s;
  }
  __syncthreads();

  // per-node attention logits
  for (int i = tid; i < 192; i += 512) {
    int n = i >> 2, h = i & 3;
    float ss = 0.f, sd = 0.f;
    for (int c = 0; c < 8; ++c) {
      float v = h1[n][h * 8 + c];
      ss += v * as1w[h * 8 + c];
      sd += v * ad1w[h * 8 + c];
    }
    a1s[n][h] = ss; a1d[n][h] = sd;
  }
  __syncthreads();

  // segment max + exp-sum per (tgt, head)
  for (int i = tid; i < 192; i += 512) {
    int n = i >> 2, h = i & 3;
    float mx = -1e30f;
    for (int p = offs[n]; p < offs[n + 1]; ++p)
      mx = fmaxf(mx, lrelu(a1s[srcl[elist[p]]][h] + a1d[n][h]));
    float sm = 0.f;
    for (int p = offs[n]; p < offs[n + 1]; ++p)
      sm += expf(lrelu(a1s[srcl[elist[p]]][h] + a1d[n][h]) - mx);
    m1[n][h] = mx; d1[n][h] = sm;
  }
  __syncthreads();

  // weighted aggregation + bias + ReLU -> x2 (48x32)
  for (int i = tid; i < 1536; i += 512) {
    int n = i >> 5, j = i & 31, h = j >> 3;
    float acc = 0.f;
    for (int p = offs[n]; p < offs[n + 1]; ++p) {
      int s = srcl[elist[p]];
      float pw = expf(lrelu(a1s[s][h] + a1d[n][h]) - m1[n][h]);
      acc += pw * h1[s][j];
    }
    x2[n][j] = fmaxf(acc / (d1[n][h] + 1e-16f) + b1[j], 0.f);
  }
  __syncthreads();

  // GAT2: h2s = x2 @ W2  (48x9), single head
  for (int i = tid; i < 432; i += 512) {
    int n = i / 9, k = i % 9;
    float s = 0.f;
    for (int c = 0; c < 32; ++c) s += x2[n][c] * W2[c * 9 + k];
    h2s[n][k] = s;
  }
  __syncthreads();
  if (tid < 48) {
    float ss = 0.f, sd = 0.f;
    for (int k = 0; k < 9; ++k) { ss += h2s[tid][k] * as2w[k]; sd += h2s[tid][k] * ad2w[k]; }
    a2s[tid] = ss; a2d[tid] = sd;
  }
  __syncthreads();
  if (tid < 48) {
    int n = tid;
    float mx = -1e30f;
    for (int p = offs[n]; p < offs[n + 1]; ++p)
      mx = fmaxf(mx, lrelu(a2s[srcl[elist[p]]] + a2d[n]));
    float sm = 0.f;
    for (int p = offs[n]; p < offs[n + 1]; ++p)
      sm += expf(lrelu(a2s[srcl[elist[p]]] + a2d[n]) - mx);
    m2[n] = mx; d2[n] = sm;
  }
  __syncthreads();
  for (int i = tid; i < 432; i += 512) {
    int n = i / 9, k = i % 9;
    float acc = 0.f;
    for (int p = offs[n]; p < offs[n + 1]; ++p) {
      int s = srcl[elist[p]];
      acc += expf(lrelu(a2s[s] + a2d[n]) - m2[n]) * h2s[s][k];
    }
    g2[n][k] = acc / (d2[n] + 1e-16f) + b2[k];   // mean over 1 head = identity
  }
  __syncthreads();

  // LayerNorm(9) + residual
  if (tid < 48) {
    float mu = 0.f;
    for (int k = 0; k < 9; ++k) mu += g2[tid][k];
    mu *= (1.f / 9.f);
    float var = 0.f;
    for (int k = 0; k < 9; ++k) { float dd = g2[tid][k] - mu; var += dd * dd; }
    var *= (1.f / 9.f);
    float is = rsqrtf(var + EPS_LN);
    for (int k = 0; k < 9; ++k)
      xl[tid][k] = lng[k] * (g2[tid][k] - mu) * is + lnb[k] + xin[tid][k];
  }
  __syncthreads();

  // Linear (9 -> 2048) + ReLU -> hlin (48 x 2048)
  for (int i = tid; i < 48 * 2048; i += 512) {
    int n = i >> 11, j = i & 2047;
    float s = linb[j];
    for (int k = 0; k < 9; ++k) s += xl[n][k] * linW[k * 2048 + j];
    hlin[i] = fmaxf(s, 0.f);
  }
}

// ---------------------------------------------------------------------------
// Kernel C: ConvTranspose3d (32->16, k=4, s=2, p=1): (48,32,4^3) -> (48,16,8^3)
// Block = (co, n); 64 threads, one (od,oh) row of 8 outputs each.
// out[od] gets taps kd with (od+1-kd) even, id=(od+1-kd)/2 in [0,4).
// ---------------------------------------------------------------------------
__global__ __launch_bounds__(64) void kC(
    const float* __restrict__ hlin, const float* __restrict__ w,
    const float* __restrict__ bias, float* __restrict__ outp)
{
  const int co = blockIdx.x, n = blockIdx.y, tid = threadIdx.x;
  __shared__ float xs[2048];   // [32][4][4][4]
  __shared__ float wsd[2048];  // [32][4][4][4] slice for this co
  for (int q = tid; q < 2048; q += 64) xs[q] = hlin[n * 2048 + q];
  for (int q = tid; q < 2048; q += 64) {
    int ci = q >> 6, t = q & 63;
    wsd[q] = w[ci * 1024 + co * 64 + t];   // W[ci][co][t]
  }
  __syncthreads();

  const int od = tid >> 3, oh = tid & 7;
  float acc[8];
#pragma unroll
  for (int i = 0; i < 8; ++i) acc[i] = 0.f;
  const int kd0 = 1 - (od & 1), kh0 = 1 - (oh & 1);
#pragma unroll
  for (int kdi = 0; kdi < 2; ++kdi) {
    int kd = kd0 + 2 * kdi;
    int id = (od + 1 - kd) >> 1;
    if ((unsigned)id >= 4u) continue;
#pragma unroll
    for (int khi = 0; khi < 2; ++khi) {
      int kh = kh0 + 2 * khi;
      int ih = (oh + 1 - kh) >> 1;
      if ((unsigned)ih >= 4u) continue;
      for (int ci = 0; ci < 32; ++ci) {
        const float* xr = &xs[ci * 64 + id * 16 + ih * 4];
        const float* wr = &wsd[ci * 64 + kd * 16 + kh * 4];
        float xv[4], wv[4];
#pragma unroll
        for (int t = 0; t < 4; ++t) { xv[t] = xr[t]; wv[t] = wr[t]; }
#pragma unroll
        for (int ow = 0; ow < 8; ++ow) {             // compile-time tap masks
          const int kw0 = 1 - (ow & 1);
          const int iw0 = (ow + 1 - kw0) >> 1;
          if (iw0 < 4) acc[ow] += xv[iw0] * wv[kw0];
          if (iw0 - 1 >= 0) acc[ow] += xv[iw0 - 1] * wv[kw0 + 2];
        }
      }
    }
  }
  const float bb = bias[co];
  float* op = &outp[(n * 16 + co) * 512 + od * 64 + oh * 8];
#pragma unroll
  for (int ow = 0; ow < 8; ++ow) op[ow] = fmaxf(acc[ow] + bb, 0.f);  // +bias, ReLU
}

// ---------------------------------------------------------------------------
// Kernel D: ConvTranspose3d (16->9, k=4, s=2, p=1): (48,16,8^3) -> (48,9,16^3)
// Block = (co, n); 256 threads, one (od,oh) row of 16 outputs each.
// ---------------------------------------------------------------------------
__global__ __launch_bounds__(256) void kD(
    const float* __restrict__ x, const float* __restrict__ w,
    const float* __restrict__ bias, float* __restrict__ outp)
{
  const int co = blockIdx.x, n = blockIdx.y, tid = threadIdx.x;
  __shared__ float xs[8192];   // [16][8][8][8]
  __shared__ float wsd[1024];  // [16][4][4][4] slice for this co
  {
    const float4* src = (const float4*)(x + (size_t)n * 8192);
    float4* dst = (float4*)xs;
    for (int q = tid; q < 2048; q += 256) dst[q] = src[q];
  }
  for (int q = tid; q < 1024; q += 256) {
    int ci = q >> 6, t = q & 63;
    wsd[q] = w[(ci * 9 + co) * 64 + t];
  }
  __syncthreads();

  const int od = tid >> 4, oh = tid & 15;
  float acc[16];
#pragma unroll
  for (int i = 0; i < 16; ++i) acc[i] = 0.f;
  const int kd0 = 1 - (od & 1), kh0 = 1 - (oh & 1);
#pragma unroll
  for (int kdi = 0; kdi < 2; ++kdi) {
    int kd = kd0 + 2 * kdi;
    int id = (od + 1 - kd) >> 1;
    if ((unsigned)id >= 8u) continue;
#pragma unroll
    for (int khi = 0; khi < 2; ++khi) {
      int kh = kh0 + 2 * khi;
      int ih = (oh + 1 - kh) >> 1;
      if ((unsigned)ih >= 8u) continue;
      for (int ci = 0; ci < 16; ++ci) {
        const float* xr = &xs[ci * 512 + id * 64 + ih * 8];
        const float* wr = &wsd[ci * 64 + kd * 16 + kh * 4];
        float xv[8], wv[4];
#pragma unroll
        for (int t = 0; t < 8; ++t) xv[t] = xr[t];
#pragma unroll
        for (int t = 0; t < 4; ++t) wv[t] = wr[t];
#pragma unroll
        for (int ow = 0; ow < 16; ++ow) {
          const int kw0 = 1 - (ow & 1);
          const int iw0 = (ow + 1 - kw0) >> 1;
          if (iw0 < 8) acc[ow] += xv[iw0] * wv[kw0];
          if (iw0 - 1 >= 0) acc[ow] += xv[iw0 - 1] * wv[kw0 + 2];
        }
      }
    }
  }
  const float bb = bias[co];
  float4* op = (float4*)(outp + (size_t)(n * 9 + co) * 4096 + od * 256 + oh * 16);
#pragma unroll
  for (int t = 0; t < 4; ++t) {
    float4 v;
    v.x = acc[4 * t] + bb; v.y = acc[4 * t + 1] + bb;
    v.z = acc[4 * t + 2] + bb; v.w = acc[4 * t + 3] + bb;
    op[t] = v;
  }
}

// ---------------------------------------------------------------------------
// Kernel E: BatchNorm3d stats (training mode, biased) over (N,D,H,W) per
// channel -> affine A[c], B[c] so BN(v) = A*v + B.
// ---------------------------------------------------------------------------
__global__ __launch_bounds__(256) void kE(
    const float* __restrict__ h2, const float* __restrict__ bng,
    const float* __restrict__ bnb, float* __restrict__ AB)
{
  const int c = blockIdx.x, tid = threadIdx.x;
  __shared__ float rs[256], rq[256];
  float s = 0.f, q = 0.f;
  for (int i = tid; i < 48 * 4096; i += 256) {
    int n = i >> 12, z = i & 4095;
    float v = h2[(size_t)(n * 9 + c) * 4096 + z];
    s += v; q += v * v;
  }
  rs[tid] = s; rq[tid] = q;
  __syncthreads();
  for (int off = 128; off > 0; off >>= 1) {
    if (tid < off) { rs[tid] += rs[tid + off]; rq[tid] += rq[tid + off]; }
    __syncthreads();
  }
  if (tid == 0) {
    float mean = rs[0] * (1.f / 196608.f);
    float var = rq[0] * (1.f / 196608.f) - mean * mean;
    float Aa = bng[c] * rsqrtf(var + EPS_BN);
    AB[c] = Aa;
    AB[9 + c] = bnb[c] - Aa * mean;
  }
}

// ---------------------------------------------------------------------------
// Kernel F: out = volumes + scale * (A_c * trilinear16->64(h2) + B_c)
// Half-pixel (align_corners=False); scale=0.25 so src = 0.25*o - 0.375.
// Block = (od-slab of 8, c, n); stages the 16^3 channel (16 KB) in LDS.
// Each thread handles float4 groups along ow; a group ow=4k..4k+3 needs
// zy-interp at x in {k-1,k,k+1} (edge-clamped), fracs {5/8,7/8,1/8,3/8}.
// ---------------------------------------------------------------------------
__device__ __forceinline__ void axis16(int o, int& i0, int& i1, float& f) {
  int t = 2 * o - 3;                      // 8*src
  int q = (t >= 0) ? (t >> 3) : -1;       // floor(t/8); t >= -3 so floor=-1
  f = (float)(t - 8 * q) * 0.125f;
  i0 = q < 0 ? 0 : q;
  i1 = q + 1 > 15 ? 15 : q + 1;
}

__global__ __launch_bounds__(256) void kF(
    const float* __restrict__ vol, const float* __restrict__ h2,
    const float* __restrict__ AB, const float* __restrict__ scp,
    float* __restrict__ outp)
{
  const int slab = blockIdx.x, c = blockIdx.y, n = blockIdx.z, tid = threadIdx.x;
  __shared__ float hs[4096];   // h2[n][c] : [16][16][16]
  {
    const float4* src = (const float4*)(h2 + (size_t)(n * 9 + c) * 4096);
    float4* dst = (float4*)hs;
#pragma unroll
    for (int t = 0; t < 4; ++t) dst[tid + 256 * t] = src[tid + 256 * t];
  }
  const float Aa = AB[c], Bb = AB[9 + c], sc = scp[0];
  __syncthreads();

  const int od_base = slab * 8;
  const size_t gbase = ((size_t)(n * 9 + c) * 64 + od_base) * 1024;  // float4 units
  const float4* v4 = (const float4*)vol;
  float4* o4 = (float4*)outp;

  for (int it = 0; it < 32; ++it) {
    int u = tid + it * 256;                 // 0..8191 within slab
    int owq = u & 15, oh = (u >> 4) & 63, odl = u >> 10;
    int z0, z1, y0, y1; float fz, fy;
    axis16(od_base + odl, z0, z1, fz);
    axis16(oh, y0, y1, fy);
    float w00 = (1.f - fz) * (1.f - fy), w01 = (1.f - fz) * fy;
    float w10 = fz * (1.f - fy), w11 = fz * fy;
    int bz0 = z0 << 8, bz1 = z1 << 8, by0 = y0 << 4, by1 = y1 << 4;
    int xa = owq - 1 < 0 ? 0 : owq - 1;
    int xc = owq + 1 > 15 ? 15 : owq + 1;
    float a = w00 * hs[bz0 + by0 + xa] + w01 * hs[bz0 + by1 + xa]
            + w10 * hs[bz1 + by0 + xa] + w11 * hs[bz1 + by1 + xa];
    float b = w00 * hs[bz0 + by0 + owq] + w01 * hs[bz0 + by1 + owq]
            + w10 * hs[bz1 + by0 + owq] + w11 * hs[bz1 + by1 + owq];
    float cc = w00 * hs[bz0 + by0 + xc] + w01 * hs[bz0 + by1 + xc]
             + w10 * hs[bz1 + by0 + xc] + w11 * hs[bz1 + by1 + xc];
    float p0 = a + 0.625f * (b - a);
    float p1 = a + 0.875f * (b - a);
    float p2 = b + 0.125f * (cc - b);
    float p3 = b + 0.375f * (cc - b);
    size_t g = gbase + (size_t)u;
    float4 vv = v4[g];
    float4 oo;
    oo.x = vv.x + sc * fmaf(Aa, p0, Bb);
    oo.y = vv.y + sc * fmaf(Aa, p1, Bb);
    oo.z = vv.z + sc * fmaf(Aa, p2, Bb);
    oo.w = vv.w + sc * fmaf(Aa, p3, Bb);
    o4[g] = oo;
  }
}

// ---------------------------------------------------------------------------
extern "C" void kernel_launch(void* const* d_in, const int* in_sizes, int n_in,
                              void* d_out, int out_size, void* d_ws, size_t ws_size,
                              hipStream_t stream) {
  (void)in_sizes; (void)n_in; (void)out_size; (void)ws_size;
  const float* obj  = (const float*)d_in[0];
  const int*   eidx = (const int*)d_in[1];
  const float* vol  = (const float*)d_in[2];
  const float* W1   = (const float*)d_in[3];
  const float* as1  = (const float*)d_in[4];
  const float* ad1  = (const float*)d_in[5];
  const float* b1   = (const float*)d_in[6];
  const float* W2   = (const float*)d_in[7];
  const float* as2  = (const float*)d_in[8];
  const float* ad2  = (const float*)d_in[9];
  const float* b2   = (const float*)d_in[10];
  const float* lng  = (const float*)d_in[11];
  const float* lnb  = (const float*)d_in[12];
  const float* scp  = (const float*)d_in[13];
  const float* linW = (const float*)d_in[14];
  const float* linb = (const float*)d_in[15];
  const float* ct1W = (const float*)d_in[16];
  const float* ct1b = (const float*)d_in[17];
  const float* ct2W = (const float*)d_in[18];
  const float* ct2b = (const float*)d_in[19];
  const float* bng  = (const float*)d_in[20];
  const float* bnb  = (const float*)d_in[21];

  float* ws   = (float*)d_ws;
  float* hlin = ws;                 // 48*2048          =   98304 f
  float* hct1 = ws + 98304;         // 48*16*512        =  393216 f
  float* h2   = ws + 491520;        // 48*9*4096        = 1769472 f
  float* AB   = ws + 2260992;       // 18 f  (~9.05 MB total)

  float* out = (float*)d_out;

  kA<<<1, 512, 0, stream>>>(obj, eidx, W1, as1, ad1, b1, W2, as2, ad2, b2,
                            lng, lnb, linW, linb, hlin);
  kC<<<dim3(16, 48), 64, 0, stream>>>(hlin, ct1W, ct1b, hct1);
  kD<<<dim3(9, 48), 256, 0, stream>>>(hct1, ct2W, ct2b, h2);
  kE<<<9, 256, 0, stream>>>(h2, bng, bnb, AB);
  kF<<<dim3(8, 9, 48), 256, 0, stream>>>(vol, h2, AB, scp, out);
}

// Round 5
// 308.478 us; speedup vs baseline: 1.8075x; 1.8075x over previous
//
#include <hip/hip_runtime.h>

#define EPS_LN 1e-5f
#define EPS_BN 1e-5f

__device__ __forceinline__ float lrelu(float v) { return v >= 0.f ? v : 0.2f * v; }

// ---------------------------------------------------------------------------
// Kernel A: GAT1 (+ReLU) -> GAT2 -> LayerNorm + residual  -> xl (48x9) to ws
// Single block; N=48, E=768+48 self loops = 816. Everything lives in LDS.
// (Linear 9->2048 split out to kB: it was latency-bound on one CU.)
// ---------------------------------------------------------------------------
__global__ __launch_bounds__(512) void kA(
    const float* __restrict__ obj, const int* __restrict__ eidx,
    const float* __restrict__ W1, const float* __restrict__ as1w,
    const float* __restrict__ ad1w, const float* __restrict__ b1,
    const float* __restrict__ W2, const float* __restrict__ as2w,
    const float* __restrict__ ad2w, const float* __restrict__ b2,
    const float* __restrict__ lng, const float* __restrict__ lnb,
    float* __restrict__ xlg)
{
  const int tid = threadIdx.x;
  __shared__ float xin[48][9];
  __shared__ float h1[48][32];
  __shared__ float a1s[48][4], a1d[48][4];
  __shared__ float m1[48][4], d1[48][4];
  __shared__ float x2[48][32];
  __shared__ float h2s[48][9];
  __shared__ float a2s[48], a2d[48], m2[48], d2[48];
  __shared__ float g2[48][9];
  __shared__ int srcl[816], tgtl[816], elist[816];
  __shared__ int offs[49], cnt[48];

  for (int i = tid; i < 768; i += 512) { srcl[i] = eidx[i]; tgtl[i] = eidx[768 + i]; }
  if (tid < 48) { srcl[768 + tid] = tid; tgtl[768 + tid] = tid; }   // self loops
  for (int i = tid; i < 432; i += 512) xin[i / 9][i % 9] = obj[i];
  __syncthreads();

  // CSR over target nodes (deterministic edge order)
  if (tid < 48) { int c = 0; for (int e = 0; e < 816; ++e) c += (tgtl[e] == tid); cnt[tid] = c; }
  __syncthreads();
  if (tid == 0) { offs[0] = 0; for (int n = 0; n < 48; ++n) offs[n + 1] = offs[n] + cnt[n]; }
  __syncthreads();
  if (tid < 48) { int p = offs[tid]; for (int e = 0; e < 816; ++e) if (tgtl[e] == tid) elist[p++] = e; }

  // h1 = x @ W1  (48x32)
  for (int i = tid; i < 1536; i += 512) {
    int n = i >> 5, j = i & 31;
    float s = 0.f;
    for (int f = 0; f < 9; ++f) s += xin[n][f] * W1[f * 32 + j];
    h1[n][j] = s;
  }
  __syncthreads();

  // per-node attention logits
  for (int i = tid; i < 192; i += 512) {
    int n = i >> 2, h = i & 3;
    float ss = 0.f, sd = 0.f;
    for (int c = 0; c < 8; ++c) {
      float v = h1[n][h * 8 + c];
      ss += v * as1w[h * 8 + c];
      sd += v * ad1w[h * 8 + c];
    }
    a1s[n][h] = ss; a1d[n][h] = sd;
  }
  __syncthreads();

  // segment max + exp-sum per (tgt, head)
  for (int i = tid; i < 192; i += 512) {
    int n = i >> 2, h = i & 3;
    float mx = -1e30f;
    for (int p = offs[n]; p < offs[n + 1]; ++p)
      mx = fmaxf(mx, lrelu(a1s[srcl[elist[p]]][h] + a1d[n][h]));
    float sm = 0.f;
    for (int p = offs[n]; p < offs[n + 1]; ++p)
      sm += expf(lrelu(a1s[srcl[elist[p]]][h] + a1d[n][h]) - mx);
    m1[n][h] = mx; d1[n][h] = sm;
  }
  __syncthreads();

  // weighted aggregation + bias + ReLU -> x2 (48x32)
  for (int i = tid; i < 1536; i += 512) {
    int n = i >> 5, j = i & 31, h = j >> 3;
    float acc = 0.f;
    for (int p = offs[n]; p < offs[n + 1]; ++p) {
      int s = srcl[elist[p]];
      float pw = expf(lrelu(a1s[s][h] + a1d[n][h]) - m1[n][h]);
      acc += pw * h1[s][j];
    }
    x2[n][j] = fmaxf(acc / (d1[n][h] + 1e-16f) + b1[j], 0.f);
  }
  __syncthreads();

  // GAT2: h2s = x2 @ W2  (48x9), single head
  for (int i = tid; i < 432; i += 512) {
    int n = i / 9, k = i % 9;
    float s = 0.f;
    for (int c = 0; c < 32; ++c) s += x2[n][c] * W2[c * 9 + k];
    h2s[n][k] = s;
  }
  __syncthreads();
  if (tid < 48) {
    float ss = 0.f, sd = 0.f;
    for (int k = 0; k < 9; ++k) { ss += h2s[tid][k] * as2w[k]; sd += h2s[tid][k] * ad2w[k]; }
    a2s[tid] = ss; a2d[tid] = sd;
  }
  __syncthreads();
  if (tid < 48) {
    int n = tid;
    float mx = -1e30f;
    for (int p = offs[n]; p < offs[n + 1]; ++p)
      mx = fmaxf(mx, lrelu(a2s[srcl[elist[p]]] + a2d[n]));
    float sm = 0.f;
    for (int p = offs[n]; p < offs[n + 1]; ++p)
      sm += expf(lrelu(a2s[srcl[elist[p]]] + a2d[n]) - mx);
    m2[n] = mx; d2[n] = sm;
  }
  __syncthreads();
  for (int i = tid; i < 432; i += 512) {
    int n = i / 9, k = i % 9;
    float acc = 0.f;
    for (int p = offs[n]; p < offs[n + 1]; ++p) {
      int s = srcl[elist[p]];
      acc += expf(lrelu(a2s[s] + a2d[n]) - m2[n]) * h2s[s][k];
    }
    g2[n][k] = acc / (d2[n] + 1e-16f) + b2[k];   // mean over 1 head = identity
  }
  __syncthreads();

  // LayerNorm(9) + residual -> global xl
  if (tid < 48) {
    float mu = 0.f;
    for (int k = 0; k < 9; ++k) mu += g2[tid][k];
    mu *= (1.f / 9.f);
    float var = 0.f;
    for (int k = 0; k < 9; ++k) { float dd = g2[tid][k] - mu; var += dd * dd; }
    var *= (1.f / 9.f);
    float is = rsqrtf(var + EPS_LN);
    for (int k = 0; k < 9; ++k)
      xlg[tid * 9 + k] = lng[k] * (g2[tid][k] - mu) * is + lnb[k] + xin[tid][k];
  }
}

// ---------------------------------------------------------------------------
// Kernel B: Linear (9 -> 2048) + ReLU.  One block per node (48 blocks x 256).
// ---------------------------------------------------------------------------
__global__ __launch_bounds__(256) void kB(
    const float* __restrict__ xlg, const float* __restrict__ linW,
    const float* __restrict__ linb, float* __restrict__ hlin)
{
  const int n = blockIdx.x, tid = threadIdx.x;
  __shared__ float xls[9];
  if (tid < 9) xls[tid] = xlg[n * 9 + tid];
  __syncthreads();
#pragma unroll
  for (int m = 0; m < 8; ++m) {
    int j = tid + m * 256;
    float s = linb[j];
#pragma unroll
    for (int k = 0; k < 9; ++k) s += xls[k] * linW[k * 2048 + j];
    hlin[n * 2048 + j] = fmaxf(s, 0.f);
  }
}

// ---------------------------------------------------------------------------
// Kernel C: ConvTranspose3d (32->16, k=4, s=2, p=1): (48,32,4^3) -> (48,16,8^3)
// Block = (co, n); 64 threads, one (od,oh) row of 8 outputs each.
// ---------------------------------------------------------------------------
__global__ __launch_bounds__(64) void kC(
    const float* __restrict__ hlin, const float* __restrict__ w,
    const float* __restrict__ bias, float* __restrict__ outp)
{
  const int co = blockIdx.x, n = blockIdx.y, tid = threadIdx.x;
  __shared__ float xs[2048];   // [32][4][4][4]
  __shared__ float wsd[2048];  // [32][4][4][4] slice for this co
  for (int q = tid; q < 2048; q += 64) xs[q] = hlin[n * 2048 + q];
  for (int q = tid; q < 2048; q += 64) {
    int ci = q >> 6, t = q & 63;
    wsd[q] = w[ci * 1024 + co * 64 + t];   // W[ci][co][t]
  }
  __syncthreads();

  const int od = tid >> 3, oh = tid & 7;
  float acc[8];
#pragma unroll
  for (int i = 0; i < 8; ++i) acc[i] = 0.f;
  const int kd0 = 1 - (od & 1), kh0 = 1 - (oh & 1);
#pragma unroll
  for (int kdi = 0; kdi < 2; ++kdi) {
    int kd = kd0 + 2 * kdi;
    int id = (od + 1 - kd) >> 1;
    if ((unsigned)id >= 4u) continue;
#pragma unroll
    for (int khi = 0; khi < 2; ++khi) {
      int kh = kh0 + 2 * khi;
      int ih = (oh + 1 - kh) >> 1;
      if ((unsigned)ih >= 4u) continue;
      for (int ci = 0; ci < 32; ++ci) {
        const float* xr = &xs[ci * 64 + id * 16 + ih * 4];
        const float* wr = &wsd[ci * 64 + kd * 16 + kh * 4];
        float xv[4], wv[4];
#pragma unroll
        for (int t = 0; t < 4; ++t) { xv[t] = xr[t]; wv[t] = wr[t]; }
#pragma unroll
        for (int ow = 0; ow < 8; ++ow) {             // compile-time tap masks
          const int kw0 = 1 - (ow & 1);
          const int iw0 = (ow + 1 - kw0) >> 1;
          if (iw0 < 4) acc[ow] += xv[iw0] * wv[kw0];
          if (iw0 - 1 >= 0) acc[ow] += xv[iw0 - 1] * wv[kw0 + 2];
        }
      }
    }
  }
  const float bb = bias[co];
  float* op = &outp[(n * 16 + co) * 512 + od * 64 + oh * 8];
#pragma unroll
  for (int ow = 0; ow < 8; ++ow) op[ow] = fmaxf(acc[ow] + bb, 0.f);  // +bias, ReLU
}

// ---------------------------------------------------------------------------
// Kernel D: ConvTranspose3d (16->9, k=4, s=2, p=1): (48,16,8^3) -> (48,9,16^3)
// Block = (co, n); 256 threads, one (od,oh) row of 16 outputs each.
// ---------------------------------------------------------------------------
__global__ __launch_bounds__(256) void kD(
    const float* __restrict__ x, const float* __restrict__ w,
    const float* __restrict__ bias, float* __restrict__ outp)
{
  const int co = blockIdx.x, n = blockIdx.y, tid = threadIdx.x;
  __shared__ float xs[8192];   // [16][8][8][8]
  __shared__ float wsd[1024];  // [16][4][4][4] slice for this co
  {
    const float4* src = (const float4*)(x + (size_t)n * 8192);
    float4* dst = (float4*)xs;
    for (int q = tid; q < 2048; q += 256) dst[q] = src[q];
  }
  for (int q = tid; q < 1024; q += 256) {
    int ci = q >> 6, t = q & 63;
    wsd[q] = w[(ci * 9 + co) * 64 + t];
  }
  __syncthreads();

  const int od = tid >> 4, oh = tid & 15;
  float acc[16];
#pragma unroll
  for (int i = 0; i < 16; ++i) acc[i] = 0.f;
  const int kd0 = 1 - (od & 1), kh0 = 1 - (oh & 1);
#pragma unroll
  for (int kdi = 0; kdi < 2; ++kdi) {
    int kd = kd0 + 2 * kdi;
    int id = (od + 1 - kd) >> 1;
    if ((unsigned)id >= 8u) continue;
#pragma unroll
    for (int khi = 0; khi < 2; ++khi) {
      int kh = kh0 + 2 * khi;
      int ih = (oh + 1 - kh) >> 1;
      if ((unsigned)ih >= 8u) continue;
      for (int ci = 0; ci < 16; ++ci) {
        const float* xr = &xs[ci * 512 + id * 64 + ih * 8];
        const float* wr = &wsd[ci * 64 + kd * 16 + kh * 4];
        float xv[8], wv[4];
#pragma unroll
        for (int t = 0; t < 8; ++t) xv[t] = xr[t];
#pragma unroll
        for (int t = 0; t < 4; ++t) wv[t] = wr[t];
#pragma unroll
        for (int ow = 0; ow < 16; ++ow) {
          const int kw0 = 1 - (ow & 1);
          const int iw0 = (ow + 1 - kw0) >> 1;
          if (iw0 < 8) acc[ow] += xv[iw0] * wv[kw0];
          if (iw0 - 1 >= 0) acc[ow] += xv[iw0 - 1] * wv[kw0 + 2];
        }
      }
    }
  }
  const float bb = bias[co];
  float4* op = (float4*)(outp + (size_t)(n * 9 + co) * 4096 + od * 256 + oh * 16);
#pragma unroll
  for (int t = 0; t < 4; ++t) {
    float4 v;
    v.x = acc[4 * t] + bb; v.y = acc[4 * t + 1] + bb;
    v.z = acc[4 * t + 2] + bb; v.w = acc[4 * t + 3] + bb;
    op[t] = v;
  }
}

// ---------------------------------------------------------------------------
// Kernel E1: per-(c,n) partial sums for BN stats. 432 blocks x 256 threads,
// float4 loads, LDS tree reduce (deterministic). -> psum[c*48+n], pssq[...].
// ---------------------------------------------------------------------------
__global__ __launch_bounds__(256) void kE1(
    const float* __restrict__ h2, float* __restrict__ psum,
    float* __restrict__ pssq)
{
  const int c = blockIdx.x, n = blockIdx.y, tid = threadIdx.x;
  __shared__ float rs[256], rq[256];
  const float4* src = (const float4*)(h2 + (size_t)(n * 9 + c) * 4096);
  float s = 0.f, q = 0.f;
#pragma unroll
  for (int t = 0; t < 4; ++t) {
    float4 v = src[tid + 256 * t];
    s += v.x + v.y + v.z + v.w;
    q += v.x * v.x + v.y * v.y + v.z * v.z + v.w * v.w;
  }
  rs[tid] = s; rq[tid] = q;
  __syncthreads();
  for (int off = 128; off > 0; off >>= 1) {
    if (tid < off) { rs[tid] += rs[tid + off]; rq[tid] += rq[tid + off]; }
    __syncthreads();
  }
  if (tid == 0) { psum[c * 48 + n] = rs[0]; pssq[c * 48 + n] = rq[0]; }
}

// ---------------------------------------------------------------------------
// Kernel E2: finalize BN affine A[c], B[c] so BN(v) = A*v + B.
// ---------------------------------------------------------------------------
__global__ __launch_bounds__(64) void kE2(
    const float* __restrict__ psum, const float* __restrict__ pssq,
    const float* __restrict__ bng, const float* __restrict__ bnb,
    float* __restrict__ AB)
{
  const int c = threadIdx.x;
  if (c >= 9) return;
  float s = 0.f, q = 0.f;
  for (int n = 0; n < 48; ++n) { s += psum[c * 48 + n]; q += pssq[c * 48 + n]; }
  float mean = s * (1.f / 196608.f);
  float var = q * (1.f / 196608.f) - mean * mean;
  float Aa = bng[c] * rsqrtf(var + EPS_BN);
  AB[c] = Aa;
  AB[9 + c] = bnb[c] - Aa * mean;
}

// ---------------------------------------------------------------------------
// Kernel F: out = volumes + scale * (A_c * trilinear16->64(h2) + B_c)
// Half-pixel; scale=0.25 so src = 0.25*o - 0.375. Stages 16^3 channel in LDS;
// float4 group ow=4k..4k+3 needs zy-interp at x in {k-1,k,k+1}, edge-clamped.
// ---------------------------------------------------------------------------
__device__ __forceinline__ void axis16(int o, int& i0, int& i1, float& f) {
  int t = 2 * o - 3;                      // 8*src
  int q = (t >= 0) ? (t >> 3) : -1;       // floor(t/8); t >= -3 so floor=-1
  f = (float)(t - 8 * q) * 0.125f;
  i0 = q < 0 ? 0 : q;
  i1 = q + 1 > 15 ? 15 : q + 1;
}

__global__ __launch_bounds__(256) void kF(
    const float* __restrict__ vol, const float* __restrict__ h2,
    const float* __restrict__ AB, const float* __restrict__ scp,
    float* __restrict__ outp)
{
  const int slab = blockIdx.x, c = blockIdx.y, n = blockIdx.z, tid = threadIdx.x;
  __shared__ float hs[4096];   // h2[n][c] : [16][16][16]
  {
    const float4* src = (const float4*)(h2 + (size_t)(n * 9 + c) * 4096);
    float4* dst = (float4*)hs;
#pragma unroll
    for (int t = 0; t < 4; ++t) dst[tid + 256 * t] = src[tid + 256 * t];
  }
  const float Aa = AB[c], Bb = AB[9 + c], sc = scp[0];
  __syncthreads();

  const int od_base = slab * 8;
  const size_t gbase = ((size_t)(n * 9 + c) * 64 + od_base) * 1024;  // float4 units
  const float4* v4 = (const float4*)vol;
  float4* o4 = (float4*)outp;

  for (int it = 0; it < 32; ++it) {
    int u = tid + it * 256;                 // 0..8191 within slab
    int owq = u & 15, oh = (u >> 4) & 63, odl = u >> 10;
    int z0, z1, y0, y1; float fz, fy;
    axis16(od_base + odl, z0, z1, fz);
    axis16(oh, y0, y1, fy);
    float w00 = (1.f - fz) * (1.f - fy), w01 = (1.f - fz) * fy;
    float w10 = fz * (1.f - fy), w11 = fz * fy;
    int bz0 = z0 << 8, bz1 = z1 << 8, by0 = y0 << 4, by1 = y1 << 4;
    int xa = owq - 1 < 0 ? 0 : owq - 1;
    int xc = owq + 1 > 15 ? 15 : owq + 1;
    float a = w00 * hs[bz0 + by0 + xa] + w01 * hs[bz0 + by1 + xa]
            + w10 * hs[bz1 + by0 + xa] + w11 * hs[bz1 + by1 + xa];
    float b = w00 * hs[bz0 + by0 + owq] + w01 * hs[bz0 + by1 + owq]
            + w10 * hs[bz1 + by0 + owq] + w11 * hs[bz1 + by1 + owq];
    float cc = w00 * hs[bz0 + by0 + xc] + w01 * hs[bz0 + by1 + xc]
             + w10 * hs[bz1 + by0 + xc] + w11 * hs[bz1 + by1 + xc];
    float p0 = a + 0.625f * (b - a);
    float p1 = a + 0.875f * (b - a);
    float p2 = b + 0.125f * (cc - b);
    float p3 = b + 0.375f * (cc - b);
    size_t g = gbase + (size_t)u;
    float4 vv = v4[g];
    float4 oo;
    oo.x = vv.x + sc * fmaf(Aa, p0, Bb);
    oo.y = vv.y + sc * fmaf(Aa, p1, Bb);
    oo.z = vv.z + sc * fmaf(Aa, p2, Bb);
    oo.w = vv.w + sc * fmaf(Aa, p3, Bb);
    o4[g] = oo;
  }
}

// ---------------------------------------------------------------------------
extern "C" void kernel_launch(void* const* d_in, const int* in_sizes, int n_in,
                              void* d_out, int out_size, void* d_ws, size_t ws_size,
                              hipStream_t stream) {
  (void)in_sizes; (void)n_in; (void)out_size; (void)ws_size;
  const float* obj  = (const float*)d_in[0];
  const int*   eidx = (const int*)d_in[1];
  const float* vol  = (const float*)d_in[2];
  const float* W1   = (const float*)d_in[3];
  const float* as1  = (const float*)d_in[4];
  const float* ad1  = (const float*)d_in[5];
  const float* b1   = (const float*)d_in[6];
  const float* W2   = (const float*)d_in[7];
  const float* as2  = (const float*)d_in[8];
  const float* ad2  = (const float*)d_in[9];
  const float* b2   = (const float*)d_in[10];
  const float* lng  = (const float*)d_in[11];
  const float* lnb  = (const float*)d_in[12];
  const float* scp  = (const float*)d_in[13];
  const float* linW = (const float*)d_in[14];
  const float* linb = (const float*)d_in[15];
  const float* ct1W = (const float*)d_in[16];
  const float* ct1b = (const float*)d_in[17];
  const float* ct2W = (const float*)d_in[18];
  const float* ct2b = (const float*)d_in[19];
  const float* bng  = (const float*)d_in[20];
  const float* bnb  = (const float*)d_in[21];

  float* ws   = (float*)d_ws;
  float* xlg  = ws;                  // 432 f (1728 B, 16B-aligned)
  float* hlin = ws + 432;            // 48*2048   =   98304 f
  float* hct1 = ws + 98736;          // 48*16*512 =  393216 f
  float* h2   = ws + 491952;         // 48*9*4096 = 1769472 f
  float* psum = ws + 2261424;        // 432 f
  float* pssq = ws + 2261856;        // 432 f
  float* AB   = ws + 2262288;        // 18 f   (~9.05 MB total)

  float* out = (float*)d_out;

  kA<<<1, 512, 0, stream>>>(obj, eidx, W1, as1, ad1, b1, W2, as2, ad2, b2,
                            lng, lnb, xlg);
  kB<<<48, 256, 0, stream>>>(xlg, linW, linb, hlin);
  kC<<<dim3(16, 48), 64, 0, stream>>>(hlin, ct1W, ct1b, hct1);
  kD<<<dim3(9, 48), 256, 0, stream>>>(hct1, ct2W, ct2b, h2);
  kE1<<<dim3(9, 48), 256, 0, stream>>>(h2, psum, pssq);
  kE2<<<1, 64, 0, stream>>>(psum, pssq, bng, bnb, AB);
  kF<<<dim3(8, 9, 48), 256, 0, stream>>>(vol, h2, AB, scp, out);
}

// Round 6
// 301.489 us; speedup vs baseline: 1.8494x; 1.0232x over previous
//
#include <hip/hip_runtime.h>

#define EPS_LN 1e-5f
#define EPS_BN 1e-5f

typedef float f4 __attribute__((ext_vector_type(4)));

__device__ __forceinline__ float lrelu(float v) { return v >= 0.f ? v : 0.2f * v; }

// ---------------------------------------------------------------------------
// Kernel A: GAT1 (+ReLU) -> GAT2 -> LayerNorm + residual -> xl (48x9) to ws
// Single block; N=48, E=768+48 self loops = 816. Everything lives in LDS.
// ---------------------------------------------------------------------------
__global__ __launch_bounds__(512) void kA(
    const float* __restrict__ obj, const int* __restrict__ eidx,
    const float* __restrict__ W1, const float* __restrict__ as1w,
    const float* __restrict__ ad1w, const float* __restrict__ b1,
    const float* __restrict__ W2, const float* __restrict__ as2w,
    const float* __restrict__ ad2w, const float* __restrict__ b2,
    const float* __restrict__ lng, const float* __restrict__ lnb,
    float* __restrict__ xlg)
{
  const int tid = threadIdx.x;
  __shared__ float xin[48][9];
  __shared__ float h1[48][32];
  __shared__ float a1s[48][4], a1d[48][4];
  __shared__ float m1[48][4], d1[48][4];
  __shared__ float x2[48][32];
  __shared__ float h2s[48][9];
  __shared__ float a2s[48], a2d[48], m2[48], d2[48];
  __shared__ float g2[48][9];
  __shared__ int srcl[816], tgtl[816], elist[816];
  __shared__ int offs[49], cnt[48];

  for (int i = tid; i < 768; i += 512) { srcl[i] = eidx[i]; tgtl[i] = eidx[768 + i]; }
  if (tid < 48) { srcl[768 + tid] = tid; tgtl[768 + tid] = tid; }   // self loops
  for (int i = tid; i < 432; i += 512) xin[i / 9][i % 9] = obj[i];
  __syncthreads();

  // CSR over target nodes (deterministic edge order)
  if (tid < 48) { int c = 0; for (int e = 0; e < 816; ++e) c += (tgtl[e] == tid); cnt[tid] = c; }
  __syncthreads();
  if (tid == 0) { offs[0] = 0; for (int n = 0; n < 48; ++n) offs[n + 1] = offs[n] + cnt[n]; }
  __syncthreads();
  if (tid < 48) { int p = offs[tid]; for (int e = 0; e < 816; ++e) if (tgtl[e] == tid) elist[p++] = e; }

  // h1 = x @ W1  (48x32)
  for (int i = tid; i < 1536; i += 512) {
    int n = i >> 5, j = i & 31;
    float s = 0.f;
    for (int f = 0; f < 9; ++f) s += xin[n][f] * W1[f * 32 + j];
    h1[n][j] = s;
  }
  __syncthreads();

  // per-node attention logits
  for (int i = tid; i < 192; i += 512) {
    int n = i >> 2, h = i & 3;
    float ss = 0.f, sd = 0.f;
    for (int c = 0; c < 8; ++c) {
      float v = h1[n][h * 8 + c];
      ss += v * as1w[h * 8 + c];
      sd += v * ad1w[h * 8 + c];
    }
    a1s[n][h] = ss; a1d[n][h] = sd;
  }
  __syncthreads();

  // segment max + exp-sum per (tgt, head)
  for (int i = tid; i < 192; i += 512) {
    int n = i >> 2, h = i & 3;
    float mx = -1e30f;
    for (int p = offs[n]; p < offs[n + 1]; ++p)
      mx = fmaxf(mx, lrelu(a1s[srcl[elist[p]]][h] + a1d[n][h]));
    float sm = 0.f;
    for (int p = offs[n]; p < offs[n + 1]; ++p)
      sm += expf(lrelu(a1s[srcl[elist[p]]][h] + a1d[n][h]) - mx);
    m1[n][h] = mx; d1[n][h] = sm;
  }
  __syncthreads();

  // weighted aggregation + bias + ReLU -> x2 (48x32)
  for (int i = tid; i < 1536; i += 512) {
    int n = i >> 5, j = i & 31, h = j >> 3;
    float acc = 0.f;
    for (int p = offs[n]; p < offs[n + 1]; ++p) {
      int s = srcl[elist[p]];
      float pw = expf(lrelu(a1s[s][h] + a1d[n][h]) - m1[n][h]);
      acc += pw * h1[s][j];
    }
    x2[n][j] = fmaxf(acc / (d1[n][h] + 1e-16f) + b1[j], 0.f);
  }
  __syncthreads();

  // GAT2: h2s = x2 @ W2  (48x9), single head
  for (int i = tid; i < 432; i += 512) {
    int n = i / 9, k = i % 9;
    float s = 0.f;
    for (int c = 0; c < 32; ++c) s += x2[n][c] * W2[c * 9 + k];
    h2s[n][k] = s;
  }
  __syncthreads();
  if (tid < 48) {
    float ss = 0.f, sd = 0.f;
    for (int k = 0; k < 9; ++k) { ss += h2s[tid][k] * as2w[k]; sd += h2s[tid][k] * ad2w[k]; }
    a2s[tid] = ss; a2d[tid] = sd;
  }
  __syncthreads();
  if (tid < 48) {
    int n = tid;
    float mx = -1e30f;
    for (int p = offs[n]; p < offs[n + 1]; ++p)
      mx = fmaxf(mx, lrelu(a2s[srcl[elist[p]]] + a2d[n]));
    float sm = 0.f;
    for (int p = offs[n]; p < offs[n + 1]; ++p)
      sm += expf(lrelu(a2s[srcl[elist[p]]] + a2d[n]) - mx);
    m2[n] = mx; d2[n] = sm;
  }
  __syncthreads();
  for (int i = tid; i < 432; i += 512) {
    int n = i / 9, k = i % 9;
    float acc = 0.f;
    for (int p = offs[n]; p < offs[n + 1]; ++p) {
      int s = srcl[elist[p]];
      acc += expf(lrelu(a2s[s] + a2d[n]) - m2[n]) * h2s[s][k];
    }
    g2[n][k] = acc / (d2[n] + 1e-16f) + b2[k];   // mean over 1 head = identity
  }
  __syncthreads();

  // LayerNorm(9) + residual -> global xl
  if (tid < 48) {
    float mu = 0.f;
    for (int k = 0; k < 9; ++k) mu += g2[tid][k];
    mu *= (1.f / 9.f);
    float var = 0.f;
    for (int k = 0; k < 9; ++k) { float dd = g2[tid][k] - mu; var += dd * dd; }
    var *= (1.f / 9.f);
    float is = rsqrtf(var + EPS_LN);
    for (int k = 0; k < 9; ++k)
      xlg[tid * 9 + k] = lng[k] * (g2[tid][k] - mu) * is + lnb[k] + xin[tid][k];
  }
}

// ---------------------------------------------------------------------------
// Kernel BC: Linear(9->2048)+ReLU recomputed per block into LDS, then
// ConvTranspose3d (32->16, k=4, s=2, p=1): -> (48,16,8^3).
// Block = (co, n); 256 threads stage, 64 threads (wave 0) do the conv,
// one (od,oh) row of 8 outputs each. Linear math identical bitwise to the
// old separate kB (same op order), so output is unchanged.
// ---------------------------------------------------------------------------
__global__ __launch_bounds__(256) void kBC(
    const float* __restrict__ xlg, const float* __restrict__ linW,
    const float* __restrict__ linb, const float* __restrict__ w,
    const float* __restrict__ bias, float* __restrict__ outp)
{
  const int co = blockIdx.x, n = blockIdx.y, tid = threadIdx.x;
  __shared__ float xls[9];
  __shared__ float xs[2048];   // relu(linear) : [32][4][4][4]
  __shared__ float wsd[2048];  // weight slice for this co
  if (tid < 9) xls[tid] = xlg[n * 9 + tid];
  for (int q = tid; q < 2048; q += 256) {
    int ci = q >> 6, t = q & 63;
    wsd[q] = w[ci * 1024 + co * 64 + t];   // W[ci][co][t]
  }
  __syncthreads();
  for (int q = tid; q < 2048; q += 256) {
    float s = linb[q];
#pragma unroll
    for (int k = 0; k < 9; ++k) s += xls[k] * linW[k * 2048 + q];
    xs[q] = fmaxf(s, 0.f);
  }
  __syncthreads();
  if (tid >= 64) return;   // conv on wave 0 only; no barriers after this

  const int od = tid >> 3, oh = tid & 7;
  float acc[8];
#pragma unroll
  for (int i = 0; i < 8; ++i) acc[i] = 0.f;
  const int kd0 = 1 - (od & 1), kh0 = 1 - (oh & 1);
#pragma unroll
  for (int kdi = 0; kdi < 2; ++kdi) {
    int kd = kd0 + 2 * kdi;
    int id = (od + 1 - kd) >> 1;
    if ((unsigned)id >= 4u) continue;
#pragma unroll
    for (int khi = 0; khi < 2; ++khi) {
      int kh = kh0 + 2 * khi;
      int ih = (oh + 1 - kh) >> 1;
      if ((unsigned)ih >= 4u) continue;
      for (int ci = 0; ci < 32; ++ci) {
        const float* xr = &xs[ci * 64 + id * 16 + ih * 4];
        const float* wr = &wsd[ci * 64 + kd * 16 + kh * 4];
        float xv[4], wv[4];
#pragma unroll
        for (int t = 0; t < 4; ++t) { xv[t] = xr[t]; wv[t] = wr[t]; }
#pragma unroll
        for (int ow = 0; ow < 8; ++ow) {             // compile-time tap masks
          const int kw0 = 1 - (ow & 1);
          const int iw0 = (ow + 1 - kw0) >> 1;
          if (iw0 < 4) acc[ow] += xv[iw0] * wv[kw0];
          if (iw0 - 1 >= 0) acc[ow] += xv[iw0 - 1] * wv[kw0 + 2];
        }
      }
    }
  }
  const float bb = bias[co];
  float* op = &outp[(n * 16 + co) * 512 + od * 64 + oh * 8];
#pragma unroll
  for (int ow = 0; ow < 8; ++ow) op[ow] = fmaxf(acc[ow] + bb, 0.f);  // +bias, ReLU
}

// ---------------------------------------------------------------------------
// Kernel D: ConvTranspose3d (16->9, k=4, s=2, p=1): (48,16,8^3) -> (48,9,16^3)
// + BN partial stats: each block covers one full (n,co) channel, so it also
// tree-reduces sum / sumsq of its outputs -> psum/pssq (deterministic).
// ---------------------------------------------------------------------------
__global__ __launch_bounds__(256) void kD(
    const float* __restrict__ x, const float* __restrict__ w,
    const float* __restrict__ bias, float* __restrict__ outp,
    float* __restrict__ psum, float* __restrict__ pssq)
{
  const int co = blockIdx.x, n = blockIdx.y, tid = threadIdx.x;
  __shared__ float xs[8192];   // [16][8][8][8]
  __shared__ float wsd[1024];  // [16][4][4][4] slice for this co
  __shared__ float rs[256], rq[256];
  {
    const float4* src = (const float4*)(x + (size_t)n * 8192);
    float4* dst = (float4*)xs;
    for (int q = tid; q < 2048; q += 256) dst[q] = src[q];
  }
  for (int q = tid; q < 1024; q += 256) {
    int ci = q >> 6, t = q & 63;
    wsd[q] = w[(ci * 9 + co) * 64 + t];
  }
  __syncthreads();

  const int od = tid >> 4, oh = tid & 15;
  float acc[16];
#pragma unroll
  for (int i = 0; i < 16; ++i) acc[i] = 0.f;
  const int kd0 = 1 - (od & 1), kh0 = 1 - (oh & 1);
#pragma unroll
  for (int kdi = 0; kdi < 2; ++kdi) {
    int kd = kd0 + 2 * kdi;
    int id = (od + 1 - kd) >> 1;
    if ((unsigned)id >= 8u) continue;
#pragma unroll
    for (int khi = 0; khi < 2; ++khi) {
      int kh = kh0 + 2 * khi;
      int ih = (oh + 1 - kh) >> 1;
      if ((unsigned)ih >= 8u) continue;
      for (int ci = 0; ci < 16; ++ci) {
        const float* xr = &xs[ci * 512 + id * 64 + ih * 8];
        const float* wr = &wsd[ci * 64 + kd * 16 + kh * 4];
        float xv[8], wv[4];
#pragma unroll
        for (int t = 0; t < 8; ++t) xv[t] = xr[t];
#pragma unroll
        for (int t = 0; t < 4; ++t) wv[t] = wr[t];
#pragma unroll
        for (int ow = 0; ow < 16; ++ow) {
          const int kw0 = 1 - (ow & 1);
          const int iw0 = (ow + 1 - kw0) >> 1;
          if (iw0 < 8) acc[ow] += xv[iw0] * wv[kw0];
          if (iw0 - 1 >= 0) acc[ow] += xv[iw0 - 1] * wv[kw0 + 2];
        }
      }
    }
  }
  const float bb = bias[co];
  float s = 0.f, q = 0.f;
  float4* op = (float4*)(outp + (size_t)(n * 9 + co) * 4096 + od * 256 + oh * 16);
#pragma unroll
  for (int t = 0; t < 4; ++t) {
    float4 v;
    v.x = acc[4 * t] + bb; v.y = acc[4 * t + 1] + bb;
    v.z = acc[4 * t + 2] + bb; v.w = acc[4 * t + 3] + bb;
    op[t] = v;
    s += v.x + v.y + v.z + v.w;
    q += v.x * v.x + v.y * v.y + v.z * v.z + v.w * v.w;
  }
  rs[tid] = s; rq[tid] = q;
  __syncthreads();
  for (int off = 128; off > 0; off >>= 1) {
    if (tid < off) { rs[tid] += rs[tid + off]; rq[tid] += rq[tid + off]; }
    __syncthreads();
  }
  if (tid == 0) { psum[co * 48 + n] = rs[0]; pssq[co * 48 + n] = rq[0]; }
}

// ---------------------------------------------------------------------------
// Kernel F: out = volumes + scale * (A_c * trilinear16->64(h2) + B_c)
// BN affine (A,B) computed per-block from the 48 partials (wave-0 shuffle
// reduce, deterministic). Half-pixel; src = 0.25*o - 0.375. Stages only the
// 4 needed z-slices (4 KB) of the 16^3 channel. NT load/store on the
// vol/out stream preserves L2 for h2/psum.
// ---------------------------------------------------------------------------
__device__ __forceinline__ void axis16(int o, int& i0, int& i1, float& f) {
  int t = 2 * o - 3;                      // 8*src
  int q = (t >= 0) ? (t >> 3) : -1;       // floor(t/8); t >= -3 so floor=-1
  f = (float)(t - 8 * q) * 0.125f;
  i0 = q < 0 ? 0 : q;
  i1 = q + 1 > 15 ? 15 : q + 1;
}

__global__ __launch_bounds__(256) void kF(
    const float* __restrict__ vol, const float* __restrict__ h2,
    const float* __restrict__ psum, const float* __restrict__ pssq,
    const float* __restrict__ bng, const float* __restrict__ bnb,
    const float* __restrict__ scp, float* __restrict__ outp)
{
  const int slab = blockIdx.x, c = blockIdx.y, n = blockIdx.z, tid = threadIdx.x;
  __shared__ float hs[1024];   // 4 z-slices of h2[n][c] : [4][16][16]
  __shared__ float abS[2];
  int zb = 2 * slab - 1;
  zb = zb < 0 ? 0 : (zb > 12 ? 12 : zb);
  {
    const float4* src = (const float4*)(h2 + (size_t)(n * 9 + c) * 4096) + zb * 64;
    ((float4*)hs)[tid] = src[tid];   // 256 float4 = 4 slices
  }
  if (tid < 64) {   // BN finalize: reduce 48 partials in wave 0
    float s = (tid < 48) ? psum[c * 48 + tid] : 0.f;
    float q = (tid < 48) ? pssq[c * 48 + tid] : 0.f;
#pragma unroll
    for (int off = 32; off > 0; off >>= 1) {
      s += __shfl_down(s, off);
      q += __shfl_down(q, off);
    }
    if (tid == 0) {
      float mean = s * (1.f / 196608.f);
      float var = q * (1.f / 196608.f) - mean * mean;
      float Aa = bng[c] * rsqrtf(var + EPS_BN);
      abS[0] = Aa;
      abS[1] = bnb[c] - Aa * mean;
    }
  }
  const float sc = scp[0];
  __syncthreads();
  const float Aa = abS[0], Bb = abS[1];

  const int od_base = slab * 8;
  const size_t gbase = ((size_t)(n * 9 + c) * 64 + od_base) * 1024;  // float4 units
  const f4* v4 = (const f4*)vol;
  f4* o4 = (f4*)outp;

  for (int it = 0; it < 32; ++it) {
    int u = tid + it * 256;                 // 0..8191 within slab
    int owq = u & 15, oh = (u >> 4) & 63, odl = u >> 10;
    int z0, z1, y0, y1; float fz, fy;
    axis16(od_base + odl, z0, z1, fz);
    axis16(oh, y0, y1, fy);
    float w00 = (1.f - fz) * (1.f - fy), w01 = (1.f - fz) * fy;
    float w10 = fz * (1.f - fy), w11 = fz * fy;
    int bz0 = (z0 - zb) << 8, bz1 = (z1 - zb) << 8;
    int by0 = y0 << 4, by1 = y1 << 4;
    int xa = owq - 1 < 0 ? 0 : owq - 1;
    int xc = owq + 1 > 15 ? 15 : owq + 1;
    float a = w00 * hs[bz0 + by0 + xa] + w01 * hs[bz0 + by1 + xa]
            + w10 * hs[bz1 + by0 + xa] + w11 * hs[bz1 + by1 + xa];
    float b = w00 * hs[bz0 + by0 + owq] + w01 * hs[bz0 + by1 + owq]
            + w10 * hs[bz1 + by0 + owq] + w11 * hs[bz1 + by1 + owq];
    float cc = w00 * hs[bz0 + by0 + xc] + w01 * hs[bz0 + by1 + xc]
             + w10 * hs[bz1 + by0 + xc] + w11 * hs[bz1 + by1 + xc];
    float p0 = a + 0.625f * (b - a);
    float p1 = a + 0.875f * (b - a);
    float p2 = b + 0.125f * (cc - b);
    float p3 = b + 0.375f * (cc - b);
    size_t g = gbase + (size_t)u;
    f4 vv = __builtin_nontemporal_load(&v4[g]);
    f4 oo;
    oo.x = vv.x + sc * fmaf(Aa, p0, Bb);
    oo.y = vv.y + sc * fmaf(Aa, p1, Bb);
    oo.z = vv.z + sc * fmaf(Aa, p2, Bb);
    oo.w = vv.w + sc * fmaf(Aa, p3, Bb);
    __builtin_nontemporal_store(oo, &o4[g]);
  }
}

// ---------------------------------------------------------------------------
extern "C" void kernel_launch(void* const* d_in, const int* in_sizes, int n_in,
                              void* d_out, int out_size, void* d_ws, size_t ws_size,
                              hipStream_t stream) {
  (void)in_sizes; (void)n_in; (void)out_size; (void)ws_size;
  const float* obj  = (const float*)d_in[0];
  const int*   eidx = (const int*)d_in[1];
  const float* vol  = (const float*)d_in[2];
  const float* W1   = (const float*)d_in[3];
  const float* as1  = (const float*)d_in[4];
  const float* ad1  = (const float*)d_in[5];
  const float* b1   = (const float*)d_in[6];
  const float* W2   = (const float*)d_in[7];
  const float* as2  = (const float*)d_in[8];
  const float* ad2  = (const float*)d_in[9];
  const float* b2   = (const float*)d_in[10];
  const float* lng  = (const float*)d_in[11];
  const float* lnb  = (const float*)d_in[12];
  const float* scp  = (const float*)d_in[13];
  const float* linW = (const float*)d_in[14];
  const float* linb = (const float*)d_in[15];
  const float* ct1W = (const float*)d_in[16];
  const float* ct1b = (const float*)d_in[17];
  const float* ct2W = (const float*)d_in[18];
  const float* ct2b = (const float*)d_in[19];
  const float* bng  = (const float*)d_in[20];
  const float* bnb  = (const float*)d_in[21];

  float* ws   = (float*)d_ws;
  float* xlg  = ws;                  // 432 f (16B-aligned multiple: 432*4=1728)
  float* hct1 = ws + 432;            // 48*16*512 =  393216 f
  float* h2   = ws + 393648;         // 48*9*4096 = 1769472 f
  float* psum = ws + 2163120;        // 432 f
  float* pssq = ws + 2163552;        // 432 f   (~8.66 MB total)

  float* out = (float*)d_out;

  kA<<<1, 512, 0, stream>>>(obj, eidx, W1, as1, ad1, b1, W2, as2, ad2, b2,
                            lng, lnb, xlg);
  kBC<<<dim3(16, 48), 256, 0, stream>>>(xlg, linW, linb, ct1W, ct1b, hct1);
  kD<<<dim3(9, 48), 256, 0, stream>>>(hct1, ct2W, ct2b, h2, psum, pssq);
  kF<<<dim3(8, 9, 48), 256, 0, stream>>>(vol, h2, psum, pssq, bng, bnb, scp, out);
}